// Round 12
// baseline (3105.366 us; speedup 1.0000x reference)
//
#include <hip/hip_runtime.h>

#define BB 32
#define TT 1000
#define HH 512
#define G4 2048
#define BTH ((size_t)BB * TT * HH)  // elements per output tensor

typedef short short8 __attribute__((ext_vector_type(8)));
typedef float f32x4 __attribute__((ext_vector_type(4)));

__device__ __forceinline__ unsigned short f2bf(float f) {
    union { float f; unsigned u; } v; v.f = f;
    unsigned r = v.u + 0x7FFF + ((v.u >> 16) & 1);  // RNE; inputs finite
    return (unsigned short)(r >> 16);
}

// ring: u32 words [2 slots][8 groups][32 producers x 64 words]
// word = (bf16(h) << 16) | t  -- self-tagged, fence-free (R2/R9-proven protocol)
#define RING_WORDS (2 * 8 * 32 * 64)   // 32768 u32 = 128KB (proven within ws_size)

__global__ void lstm_init_ring(unsigned* ring) {
    int i = blockIdx.x * 256 + threadIdx.x;
    __hip_atomic_store(ring + i, 0xFFFFFFFFu, __ATOMIC_RELAXED,
                       __HIP_MEMORY_SCOPE_AGENT);
}

// LDS-ordering-only barrier (R9-validated): VMEM stays in flight.
#define LDS_BAR() do {                                      \
    asm volatile("s_waitcnt lgkmcnt(0)" ::: "memory");      \
    __builtin_amdgcn_s_barrier();                           \
    asm volatile("" ::: "memory");                          \
    __builtin_amdgcn_sched_barrier(0);                      \
} while (0)

__global__ void __launch_bounds__(256, 1)
lstm_main(const float* __restrict__ wx, const float* __restrict__ u,
          const float* __restrict__ ub, const float* __restrict__ ht0,
          const float* __restrict__ ct0, float* __restrict__ out,
          unsigned* __restrict__ ring)
{
    __shared__ __align__(16) unsigned short lds_h[16 * 512];  // 16KB, XOR-swizzled
    __shared__ float lds_gates[4 * 64];
    // streaming-poll landing zones: probes land here, NOT in VGPRs (R5 hazard
    // eliminated). Slots reused only after next step's prologue vmcnt(0).
    __shared__ __align__(16) unsigned pollbuf[2][4][8][64];   // 16KB

    const int tid  = threadIdx.x;
    const int bid  = blockIdx.x;
    const int cg   = bid & 31;   // owns h/gate cols [cg*16, cg*16+16)
    const int qb   = bid >> 5;   // owns batches [qb*4, qb*4+4)
    const int lane = tid & 63;
    const int wv   = tid >> 6;

    // ---- zero pad rows 4..15 of lds_h ----
    for (int j = 0; j < 3; ++j) {
        int idx8 = tid + j * 256;
        int r = 4 + (idx8 >> 6);
        int k = (idx8 & 63) * 8;
        short8 z = {0, 0, 0, 0, 0, 0, 0, 0};
        *(short8*)&lds_h[(r * 512 + k) ^ ((r & 7) << 3)] = z;
    }
    // ---- stage initial h (f32 -> bf16) ----
    {
        int r = wv, k = lane * 8;
        const float* src = ht0 + (size_t)(qb * 4 + r) * HH + k;
        float4 v0 = *(const float4*)src;
        float4 v1 = *(const float4*)(src + 4);
        union { short8 v8; unsigned short s[8]; } p;
        p.s[0] = f2bf(v0.x); p.s[1] = f2bf(v0.y); p.s[2] = f2bf(v0.z); p.s[3] = f2bf(v0.w);
        p.s[4] = f2bf(v1.x); p.s[5] = f2bf(v1.y); p.s[6] = f2bf(v1.z); p.s[7] = f2bf(v1.w);
        *(short8*)&lds_h[(r * 512 + k) ^ ((r & 7) << 3)] = p.v8;
    }

    // ---- preload u fragments into registers (loop-invariant) ----
    const int arow = lane & 15, ahi = lane >> 4;
    short8 breg[16];
    {
        const float* bp = u + (size_t)(wv * HH + cg * 16 + arow) * HH + ahi * 8;
#pragma unroll
        for (int kk = 0; kk < 16; ++kk) {
            float4 v0 = *(const float4*)(bp + kk * 32);
            float4 v1 = *(const float4*)(bp + kk * 32 + 4);
            union { short8 v8; unsigned short s[8]; } p;
            p.s[0] = f2bf(v0.x); p.s[1] = f2bf(v0.y); p.s[2] = f2bf(v0.z); p.s[3] = f2bf(v0.w);
            p.s[4] = f2bf(v1.x); p.s[5] = f2bf(v1.y); p.s[6] = f2bf(v1.z); p.s[7] = f2bf(v1.w);
            breg[kk] = p.v8;
        }
    }

    const int gate = lane >> 4;
    const int jc   = lane & 15;
    const float bias_r = ub[gate * HH + cg * 16 + jc];

    float c_reg = 0.f;
    if (lane < 16)
        c_reg = ct0[(size_t)(qb * 4 + wv) * HH + cg * 16 + lane];

    const size_t wx0 = (size_t)(qb * 4 + wv) * TT * G4 + gate * HH + cg * 16 + jc;
    float wx_cur = wx[wx0];
    float wx_nxt = wx[wx0 + G4];

    const size_t ob_gate = (size_t)(2 + gate) * BTH +
                           (size_t)(qb * 4 + wv) * TT * HH + cg * 16 + jc;
    const size_t ob_h = (size_t)(qb * 4 + wv) * TT * HH + cg * 16 + lane;

    const int a_off = arow * 512 + ahi * 8;
    const int a_msk = (arow & 7) << 3;

    __syncthreads();   // setup complete

// issue one probe set: 8 x global_load_lds dword; lane l of wave wv lands
// producer (8wv+i)'s word l at pollbuf[ss][wv][i][l]. aux=17 = sc0|sc1
// (bypass L1+L2, read the MALL -- same visibility as the proven AGENT loads).
#define ISSUE_SET(ss) do {                                                    \
    _Pragma("unroll")                                                         \
    for (int ii = 0; ii < 8; ++ii) {                                          \
        const unsigned* gp_ = ring + slotbase + (8 * wv + ii) * 64 + lane;    \
        __builtin_amdgcn_global_load_lds(                                     \
            (const __attribute__((address_space(1))) unsigned*)gp_,           \
            (__attribute__((address_space(3))) unsigned*)&pollbuf[ss][wv][ii][0], \
            4, 0, 17);                                                        \
    }                                                                         \
} while (0)

    for (int t = 0; t < TT; ++t) {
        // ---- phase 1: acquire h_{t-1} via streaming poll (bounded) ----
        if (t > 0) {
            const unsigned slotbase = ((unsigned)((t - 1) & 1) * 8 + (unsigned)qb) * 2048;
            const unsigned tg = (unsigned)(t - 1);
            unsigned x[8];
            bool fastok = false;
            // retire ALL prior VMEM (old by >=1 step): pollbuf slots now safe
            asm volatile("s_waitcnt vmcnt(0)" ::: "memory");
            __builtin_amdgcn_sched_barrier(0);
            ISSUE_SET(0);
            ISSUE_SET(1);
            int s = 0;
            for (int chk = 0; chk < 6; ++chk) {
                // oldest set (8 ops) retired; newer 8 stay in flight
                asm volatile("s_waitcnt vmcnt(8)" ::: "memory");
                __builtin_amdgcn_sched_barrier(0);
#pragma unroll
                for (int i = 0; i < 8; ++i)
                    x[i] = *(const volatile unsigned*)&pollbuf[s][wv][i][lane];
                int ok = 1;
#pragma unroll
                for (int i = 0; i < 8; ++i)
                    if (8 * wv + i != cg) ok &= ((x[i] & 0xFFFFu) == tg);
                if (__all(ok)) { fastok = true; break; }
                ISSUE_SET(s);
                s ^= 1;
                asm volatile("s_sleep 10" :::);   // ~640cy: stagger sampling ~RTT/2
            }
            if (!fastok) {
                // R9-proven AGENT poll (always correct; drains leftovers via
                // compiler-inserted vmcnt before first use)
                for (;;) {
#pragma unroll
                    for (int i = 0; i < 8; ++i)
                        x[i] = __hip_atomic_load(
                            ring + slotbase + (8 * wv + i) * 64 + lane,
                            __ATOMIC_RELAXED, __HIP_MEMORY_SCOPE_AGENT);
                    int ok = 1;
#pragma unroll
                    for (int i = 0; i < 8; ++i)
                        if (8 * wv + i != cg) ok &= ((x[i] & 0xFFFFu) == tg);
                    if (__all(ok)) break;
                }
            }
            // stage: word l of producer p = (batch l>>4, col l&15)
            {
                const int rr = lane >> 4, jj = lane & 15;
#pragma unroll
                for (int i = 0; i < 8; ++i) {
                    const int p = 8 * wv + i;
                    if (p != cg)
                        lds_h[(rr * 512 + p * 16 + jj) ^ (rr << 3)] =
                            (unsigned short)(x[i] >> 16);
                }
            }
        }
        LDS_BAR();   // S1 (lgkmcnt(0) covers the ds_writes; probes stay in flight)

        const float wx_use = wx_cur;
        wx_cur = wx_nxt;
        if (t + 2 < TT) wx_nxt = wx[wx0 + (size_t)(t + 2) * G4];   // R9 position

        // ---- phase 2: MFMA (R9-exact) ----
        f32x4 acc0 = {0.f, 0.f, 0.f, 0.f}, acc1 = {0.f, 0.f, 0.f, 0.f};
#pragma unroll
        for (int kk = 0; kk < 8; ++kk) {
            short8 va0 = *(const short8*)&lds_h[(a_off + kk * 32) ^ a_msk];
            short8 va1 = *(const short8*)&lds_h[(a_off + (kk + 8) * 32) ^ a_msk];
            acc0 = __builtin_amdgcn_mfma_f32_16x16x32_bf16(va0, breg[kk], acc0, 0, 0, 0);
            acc1 = __builtin_amdgcn_mfma_f32_16x16x32_bf16(va1, breg[kk + 8], acc1, 0, 0, 0);
        }
        f32x4 g = acc0 + acc1;
        if (lane < 16) {
#pragma unroll
            for (int rr = 0; rr < 4; ++rr)
                lds_gates[rr * 64 + wv * 16 + lane] = g[rr];
        }
        LDS_BAR();   // S2

        // ---- phase 3: activations, c/h update, publish (R9-exact) ----
        float gv = lds_gates[wv * 64 + lane] + wx_use + bias_r;
        float xs = (gate == 2) ? 2.f * gv : gv;
        float s  = 1.f / (1.f + __expf(-xs));
        float act = (gate == 2) ? 2.f * s - 1.f : s;  // tanh = 2*sigmoid(2x)-1

        float af = __shfl(act, (lane & 15) + 16, 64);
        float ag = __shfl(act, (lane & 15) + 32, 64);
        float ao = __shfl(act, (lane & 15) + 48, 64);
        if (lane < 16) {
            c_reg = af * c_reg + act * ag;
            float e2 = __expf(-2.f * c_reg);
            float th = 2.f / (1.f + e2) - 1.f;
            float hn = ao * th;
            unsigned short hb = f2bf(hn);
            // publish FIRST (critical inter-block path)
            unsigned pk = ((unsigned)hb << 16) | (unsigned)t;
            __hip_atomic_store(ring + ((size_t)(t & 1) * 8 + qb) * 2048 +
                                   cg * 64 + wv * 16 + lane,
                               pk, __ATOMIC_RELAXED, __HIP_MEMORY_SCOPE_AGENT);
            lds_h[(wv * 512 + cg * 16 + lane) ^ ((wv & 7) << 3)] = hb;
            out[ob_h + (size_t)t * HH] = hn;
            out[BTH + ob_h + (size_t)t * HH] = c_reg;
        }
        out[ob_gate + (size_t)t * HH] = act;
    }
#undef ISSUE_SET
}

extern "C" void kernel_launch(void* const* d_in, const int* in_sizes, int n_in,
                              void* d_out, int out_size, void* d_ws, size_t ws_size,
                              hipStream_t stream) {
    const float* wx = (const float*)d_in[0];
    const float* u  = (const float*)d_in[1];
    const float* ub = (const float*)d_in[2];
    const float* ht = (const float*)d_in[3];
    const float* ct = (const float*)d_in[4];
    float* out = (float*)d_out;
    unsigned* ring = (unsigned*)d_ws;   // 128KB, proven within ws_size

    lstm_init_ring<<<RING_WORDS / 256, 256, 0, stream>>>(ring);

    void* args[] = {(void*)&wx, (void*)&u, (void*)&ub, (void*)&ht,
                    (void*)&ct, (void*)&out, (void*)&ring};
    hipLaunchCooperativeKernel((void*)lstm_main, dim3(256), dim3(256), args, 0, stream);
}

// Round 13
// 1804.440 us; speedup vs baseline: 1.7210x; 1.7210x over previous
//
#include <hip/hip_runtime.h>

#define BB 32
#define TT 1000
#define HH 512
#define G4 2048
#define BTH ((size_t)BB * TT * HH)  // elements per output tensor

typedef short short8 __attribute__((ext_vector_type(8)));
typedef float f32x4 __attribute__((ext_vector_type(4)));

__device__ __forceinline__ unsigned short f2bf(float f) {
    union { float f; unsigned u; } v; v.f = f;
    unsigned r = v.u + 0x7FFF + ((v.u >> 16) & 1);  // RNE; inputs finite
    return (unsigned short)(r >> 16);
}

// ring: u32 words [2 slots][8 groups][32 producers x 64 words]
// word = (bf16(h) << 16) | t  -- self-tagged, fence-free (R2/R9-proven protocol)
#define RING_WORDS (2 * 8 * 32 * 64)   // 32768 u32 = 128KB (proven within ws_size)

__global__ void lstm_init_ring(unsigned* ring) {
    int i = blockIdx.x * 256 + threadIdx.x;
    __hip_atomic_store(ring + i, 0xFFFFFFFFu, __ATOMIC_RELAXED,
                       __HIP_MEMORY_SCOPE_AGENT);
}

// LDS-ordering-only barrier (R9-validated): VMEM stays in flight.
#define LDS_BAR() do {                                      \
    asm volatile("s_waitcnt lgkmcnt(0)" ::: "memory");      \
    __builtin_amdgcn_s_barrier();                           \
    asm volatile("" ::: "memory");                          \
    __builtin_amdgcn_sched_barrier(0);                      \
} while (0)

__global__ void __launch_bounds__(256, 1)
lstm_main(const float* __restrict__ wx, const float* __restrict__ u,
          const float* __restrict__ ub, const float* __restrict__ ht0,
          const float* __restrict__ ct0, float* __restrict__ out,
          unsigned* __restrict__ ring)
{
    __shared__ __align__(16) unsigned short lds_h[16 * 512];  // 16KB, XOR-swizzled
    __shared__ float lds_gates[4 * 64];

    const int tid  = threadIdx.x;
    const int bid  = blockIdx.x;
    const int cg   = bid & 31;   // owns h/gate cols [cg*16, cg*16+16)
    const int qb   = bid >> 5;   // owns batches [qb*4, qb*4+4)
    const int lane = tid & 63;
    const int wv   = tid >> 6;

    // ---- zero pad rows 4..15 of lds_h ----
    for (int j = 0; j < 3; ++j) {
        int idx8 = tid + j * 256;
        int r = 4 + (idx8 >> 6);
        int k = (idx8 & 63) * 8;
        short8 z = {0, 0, 0, 0, 0, 0, 0, 0};
        *(short8*)&lds_h[(r * 512 + k) ^ ((r & 7) << 3)] = z;
    }
    // ---- stage initial h (f32 -> bf16) ----
    {
        int r = wv, k = lane * 8;
        const float* src0 = ht0 + (size_t)(qb * 4 + r) * HH + k;
        float4 v0 = *(const float4*)src0;
        float4 v1 = *(const float4*)(src0 + 4);
        union { short8 v8; unsigned short s[8]; } p;
        p.s[0] = f2bf(v0.x); p.s[1] = f2bf(v0.y); p.s[2] = f2bf(v0.z); p.s[3] = f2bf(v0.w);
        p.s[4] = f2bf(v1.x); p.s[5] = f2bf(v1.y); p.s[6] = f2bf(v1.z); p.s[7] = f2bf(v1.w);
        *(short8*)&lds_h[(r * 512 + k) ^ ((r & 7) << 3)] = p.v8;
    }

    // ---- preload u fragments into registers (loop-invariant) ----
    const int arow = lane & 15, ahi = lane >> 4;
    short8 breg[16];
    {
        const float* bp = u + (size_t)(wv * HH + cg * 16 + arow) * HH + ahi * 8;
#pragma unroll
        for (int kk = 0; kk < 16; ++kk) {
            float4 v0 = *(const float4*)(bp + kk * 32);
            float4 v1 = *(const float4*)(bp + kk * 32 + 4);
            union { short8 v8; unsigned short s[8]; } p;
            p.s[0] = f2bf(v0.x); p.s[1] = f2bf(v0.y); p.s[2] = f2bf(v0.z); p.s[3] = f2bf(v0.w);
            p.s[4] = f2bf(v1.x); p.s[5] = f2bf(v1.y); p.s[6] = f2bf(v1.z); p.s[7] = f2bf(v1.w);
            breg[kk] = p.v8;
        }
    }

    const int gate = lane >> 4;
    const int jc   = lane & 15;
    const float bias_r = ub[gate * HH + cg * 16 + jc];

    float c_reg = 0.f;
    if (lane < 16)
        c_reg = ct0[(size_t)(qb * 4 + wv) * HH + cg * 16 + lane];

    const size_t wx0 = (size_t)(qb * 4 + wv) * TT * G4 + gate * HH + cg * 16 + jc;
    float wx_cur = wx[wx0];
    float wx_nxt = wx[wx0 + G4];

    const size_t ob_gate = (size_t)(2 + gate) * BTH +
                           (size_t)(qb * 4 + wv) * TT * HH + cg * 16 + jc;
    const size_t ob_h = (size_t)(qb * 4 + wv) * TT * HH + cg * 16 + lane;

    const int a_off = arow * 512 + ahi * 8;
    const int a_msk = (arow & 7) << 3;

    const int myp = tid >> 3;            // producer 0..31
    const int mw  = (tid & 7) * 8;       // word offset 0..56
    const int mb  = mw >> 4;
    const int mj  = mw & 15;

    __syncthreads();   // setup complete

#define LD4(v0, v1, v2, v3) do {                                               \
    v0 = __hip_atomic_load(src + 0, __ATOMIC_RELAXED, __HIP_MEMORY_SCOPE_AGENT); \
    v1 = __hip_atomic_load(src + 1, __ATOMIC_RELAXED, __HIP_MEMORY_SCOPE_AGENT); \
    v2 = __hip_atomic_load(src + 2, __ATOMIC_RELAXED, __HIP_MEMORY_SCOPE_AGENT); \
    v3 = __hip_atomic_load(src + 3, __ATOMIC_RELAXED, __HIP_MEMORY_SCOPE_AGENT); \
} while (0)
#define MATCH(v0, v1, v2, v3)                                                  \
    (((v0 & msk) == want) & ((v1 & msk) == want) &                             \
     ((v2 & msk) == want) & ((v3 & msk) == want))

    for (int t = 0; t < TT; ++t) {
        // ---- phase 1: acquire h_{t-1} via dual-stream staggered poll ----
        if (t > 0 && myp != cg) {
            const unsigned long long* src = (const unsigned long long*)
                (ring + ((size_t)((t - 1) & 1) * 8 + qb) * 2048 + myp * 64 + mw);
            const unsigned tg = (unsigned)(t - 1);
            const unsigned long long want =
                (unsigned long long)tg | ((unsigned long long)tg << 32);
            const unsigned long long msk = 0x0000FFFF0000FFFFull;
            unsigned long long q0, q1, q2, q3;
            unsigned long long a0, a1, a2, a3, b0, b1, b2, b3;
            // stream A now; stream B ~640cy later (sleep hides under A's RTT)
            LD4(a0, a1, a2, a3);
            __builtin_amdgcn_sched_barrier(0);
            __builtin_amdgcn_s_sleep(10);          // ~640cy ~= RTT/2 stagger
            __builtin_amdgcn_sched_barrier(0);
            LD4(b0, b1, b2, b3);
            for (;;) {
                // check A (waits A's vmcnt only; B stays in flight)
                if (MATCH(a0, a1, a2, a3)) { q0 = a0; q1 = a1; q2 = a2; q3 = a3; break; }
                LD4(a0, a1, a2, a3);               // reissue A
                if (MATCH(b0, b1, b2, b3)) { q0 = b0; q1 = b1; q2 = b2; q3 = b3; break; }
                LD4(b0, b1, b2, b3);               // reissue B
            }
            union { short8 v8; unsigned u[4]; } pv;
            pv.u[0] = ((unsigned)(q0 >> 16) & 0xFFFFu) | ((unsigned)(q0 >> 48) << 16);
            pv.u[1] = ((unsigned)(q1 >> 16) & 0xFFFFu) | ((unsigned)(q1 >> 48) << 16);
            pv.u[2] = ((unsigned)(q2 >> 16) & 0xFFFFu) | ((unsigned)(q2 >> 48) << 16);
            pv.u[3] = ((unsigned)(q3 >> 16) & 0xFFFFu) | ((unsigned)(q3 >> 48) << 16);
            *(short8*)&lds_h[(mb * 512 + myp * 16 + mj) ^ ((mb & 7) << 3)] = pv.v8;
        }
        LDS_BAR();   // S1: LDS ordering only (leftover poll loads stay in flight)

        const float wx_use = wx_cur;
        wx_cur = wx_nxt;
        if (t + 2 < TT) wx_nxt = wx[wx0 + (size_t)(t + 2) * G4];   // R9 position

        // ---- phase 2: MFMA (R9-exact) ----
        f32x4 acc0 = {0.f, 0.f, 0.f, 0.f}, acc1 = {0.f, 0.f, 0.f, 0.f};
#pragma unroll
        for (int kk = 0; kk < 8; ++kk) {
            short8 va0 = *(const short8*)&lds_h[(a_off + kk * 32) ^ a_msk];
            short8 va1 = *(const short8*)&lds_h[(a_off + (kk + 8) * 32) ^ a_msk];
            acc0 = __builtin_amdgcn_mfma_f32_16x16x32_bf16(va0, breg[kk], acc0, 0, 0, 0);
            acc1 = __builtin_amdgcn_mfma_f32_16x16x32_bf16(va1, breg[kk + 8], acc1, 0, 0, 0);
        }
        f32x4 g = acc0 + acc1;
        if (lane < 16) {
#pragma unroll
            for (int rr = 0; rr < 4; ++rr)
                lds_gates[rr * 64 + wv * 16 + lane] = g[rr];
        }
        LDS_BAR();   // S2: LDS ordering only

        // ---- phase 3: activations, c/h update, publish (R9-exact) ----
        float gv = lds_gates[wv * 64 + lane] + wx_use + bias_r;
        float xs = (gate == 2) ? 2.f * gv : gv;
        float s  = 1.f / (1.f + __expf(-xs));
        float act = (gate == 2) ? 2.f * s - 1.f : s;  // tanh = 2*sigmoid(2x)-1

        float af = __shfl(act, (lane & 15) + 16, 64);
        float ag = __shfl(act, (lane & 15) + 32, 64);
        float ao = __shfl(act, (lane & 15) + 48, 64);
        if (lane < 16) {
            c_reg = af * c_reg + act * ag;
            float e2 = __expf(-2.f * c_reg);
            float th = 2.f / (1.f + e2) - 1.f;
            float hn = ao * th;
            unsigned short hb = f2bf(hn);
            // publish FIRST (critical inter-block path)
            unsigned pk = ((unsigned)hb << 16) | (unsigned)t;
            __hip_atomic_store(ring + ((size_t)(t & 1) * 8 + qb) * 2048 +
                                   cg * 64 + wv * 16 + lane,
                               pk, __ATOMIC_RELAXED, __HIP_MEMORY_SCOPE_AGENT);
            lds_h[(wv * 512 + cg * 16 + lane) ^ ((wv & 7) << 3)] = hb;
            out[ob_h + (size_t)t * HH] = hn;
            out[BTH + ob_h + (size_t)t * HH] = c_reg;
        }
        out[ob_gate + (size_t)t * HH] = act;
    }
#undef LD4
#undef MATCH
}

extern "C" void kernel_launch(void* const* d_in, const int* in_sizes, int n_in,
                              void* d_out, int out_size, void* d_ws, size_t ws_size,
                              hipStream_t stream) {
    const float* wx = (const float*)d_in[0];
    const float* u  = (const float*)d_in[1];
    const float* ub = (const float*)d_in[2];
    const float* ht = (const float*)d_in[3];
    const float* ct = (const float*)d_in[4];
    float* out = (float*)d_out;
    unsigned* ring = (unsigned*)d_ws;   // 128KB, proven within ws_size

    lstm_init_ring<<<RING_WORDS / 256, 256, 0, stream>>>(ring);

    void* args[] = {(void*)&wx, (void*)&u, (void*)&ub, (void*)&ht,
                    (void*)&ct, (void*)&out, (void*)&ring};
    hipLaunchCooperativeKernel((void*)lstm_main, dim3(256), dim3(256), args, 0, stream);
}